// Round 7
// baseline (540.940 us; speedup 1.0000x reference)
//
#include <hip/hip_runtime.h>
#include <math.h>

#define BB 128
#define NN 128
#define DIN 1024
#define H1 256
#define DOUT 32
#define KCL 8
#define NPTS 128
#define MROWS (BB*NN)   // 16384
#define CSTR 130        // centsT row stride (words)
#define RSTR 132        // cost row stride (words, 16B aligned)
#define DEADKEY 0xFFFFFFFF00000000ull

__device__ __forceinline__ float gelu_exact(float v) {
    return 0.5f * v * (1.0f + erff(v * 0.70710678118654752f));
}

__device__ __forceinline__ unsigned long long mkkey(float v, int r, int j) {
    return ((unsigned long long)__float_as_uint(v) << 32) | (unsigned)((r << 7) | j);
}

__device__ __forceinline__ float readlanef(float v, int lane) {
    return __int_as_float(__builtin_amdgcn_readlane(__float_as_int(v), lane));
}

// u32 min via DPP (costs are >=0 floats: IEEE order == unsigned bit order)
template<int CTRL, int RMASK>
__device__ __forceinline__ unsigned dpp_umin_step(unsigned v) {
    unsigned t = (unsigned)__builtin_amdgcn_update_dpp((int)v, (int)v, CTRL, RMASK, 0xf, false);
    return t < v ? t : v;
}
__device__ __forceinline__ unsigned wave_umin_bcast(unsigned v) {
    v = dpp_umin_step<0x111, 0xf>(v);
    v = dpp_umin_step<0x112, 0xf>(v);
    v = dpp_umin_step<0x114, 0xf>(v);
    v = dpp_umin_step<0x118, 0xf>(v);
    v = dpp_umin_step<0x142, 0xa>(v);
    v = dpp_umin_step<0x143, 0xc>(v);
    return (unsigned)__builtin_amdgcn_readlane((int)v, 63);
}
// lane31 = min(lanes0..31), lane63 = min(lanes32..63)
__device__ __forceinline__ unsigned half_umin(unsigned v) {
    v = dpp_umin_step<0x111, 0xf>(v);
    v = dpp_umin_step<0x112, 0xf>(v);
    v = dpp_umin_step<0x114, 0xf>(v);
    v = dpp_umin_step<0x118, 0xf>(v);
    v = dpp_umin_step<0x142, 0xa>(v);
    return v;
}

// ---------------- GEMM1: h = gelu(x) @ W1 + b1 ----------------
// 128x128 tile, 8x8 microtile, BK=32, double-buffered LDS, global->reg prefetch,
// ONE barrier per K-tile. Per-output fma chain strictly ascending k (bit-identical).
__global__ __launch_bounds__(256) void mlp1_kernel(const float* __restrict__ x,
                                                   const float* __restrict__ W1,
                                                   const float* __restrict__ b1,
                                                   float* __restrict__ h) {
    __shared__ float As[2][32][132];  // [buf][k][m]
    __shared__ float Bs[2][32][132];  // [buf][k][n]
    const int bm = blockIdx.x;    // 128 row-tiles
    const int bn = blockIdx.y;    // 2 col-tiles
    const int tid = threadIdx.x;
    const int tx = tid & 15, ty = tid >> 4;

    float acc[8][8];
#pragma unroll
    for (int i = 0; i < 8; ++i)
#pragma unroll
        for (int j = 0; j < 8; ++j) acc[i][j] = 0.f;

    const int arow = tid >> 1;          // 0..127
    const int aq = (tid & 1) * 16;      // k offset 0 or 16
    const int bk = tid >> 3;            // 0..31
    const int bc = (tid & 7) * 16;      // 0..112

    const float* xrow = x + (size_t)(bm * 128 + arow) * DIN;
    const float* wbase = W1 + bn * 128;

    float4 av[4], wv[4];
#pragma unroll
    for (int i = 0; i < 4; ++i) {
        av[i] = *(const float4*)(xrow + aq + 4 * i);
        wv[i] = *(const float4*)(wbase + (size_t)bk * H1 + bc + 4 * i);
    }

    for (int t = 0; t < 32; ++t) {
        const int p = t & 1;
        // stage current regs -> buffer p
#pragma unroll
        for (int i = 0; i < 4; ++i) {
            As[p][aq + 4 * i + 0][arow] = gelu_exact(av[i].x);
            As[p][aq + 4 * i + 1][arow] = gelu_exact(av[i].y);
            As[p][aq + 4 * i + 2][arow] = gelu_exact(av[i].z);
            As[p][aq + 4 * i + 3][arow] = gelu_exact(av[i].w);
            *(float4*)&Bs[p][bk][bc + 4 * i] = wv[i];
        }
        // prefetch next tile into regs (completes under compute)
        if (t + 1 < 32) {
            const int kt = (t + 1) * 32;
#pragma unroll
            for (int i = 0; i < 4; ++i) {
                av[i] = *(const float4*)(xrow + kt + aq + 4 * i);
                wv[i] = *(const float4*)(wbase + (size_t)(kt + bk) * H1 + bc + 4 * i);
            }
        }
        __syncthreads();
        // compute on buffer p (concurrent with other waves' writes to p^1 next iter)
#pragma unroll
        for (int kk = 0; kk < 32; ++kk) {
            float a[8], b[8];
            *(float4*)&a[0] = *(const float4*)&As[p][kk][ty * 8];
            *(float4*)&a[4] = *(const float4*)&As[p][kk][ty * 8 + 4];
            *(float4*)&b[0] = *(const float4*)&Bs[p][kk][tx * 8];
            *(float4*)&b[4] = *(const float4*)&Bs[p][kk][tx * 8 + 4];
#pragma unroll
            for (int i = 0; i < 8; ++i)
#pragma unroll
                for (int j = 0; j < 8; ++j)
                    acc[i][j] = fmaf(a[i], b[j], acc[i][j]);
        }
    }

    const int row = bm * 128 + ty * 8;
    const int col = bn * 128 + tx * 8;
    float bias[8];
    *(float4*)&bias[0] = *(const float4*)(b1 + col);
    *(float4*)&bias[4] = *(const float4*)(b1 + col + 4);
#pragma unroll
    for (int i = 0; i < 8; ++i) {
        float o[8];
#pragma unroll
        for (int j = 0; j < 8; ++j) o[j] = acc[i][j] + bias[j];
        *(float4*)(h + (size_t)(row + i) * H1 + col) = *(float4*)&o[0];
        *(float4*)(h + (size_t)(row + i) * H1 + col + 4) = *(float4*)&o[4];
    }
}

// ---------------- GEMM2: feats = gelu(h) @ W2 + b2 ----------------
// 32 rows/block, transposed hsT[k][r] (stride 36), 4 rows/thread via b128.
__global__ __launch_bounds__(256) void mlp2_kernel(const float* __restrict__ h,
                                                   const float* __restrict__ W2,
                                                   const float* __restrict__ b2,
                                                   float* __restrict__ feats) {
    __shared__ float w2s[H1 * DOUT];          // 32 KB
    __shared__ __align__(16) float hsT[H1][36];  // [k][r], 36 KB
    const int blk = blockIdx.x;               // 512 blocks, 32 rows each
    const int tid = threadIdx.x;

    for (int i = tid; i < (H1 * DOUT) / 4; i += 256) {
        ((float4*)w2s)[i] = ((const float4*)W2)[i];
    }
    // stage gelu(h) transposed: thread loads 4 rows at one k (coalesced per row)
    {
        const int kb = tid & 63;        // k base lane
        const int rq = (tid >> 6) * 4;  // 0,4,8,12
        const float* hb = h + (size_t)blk * 32 * H1;
#pragma unroll
        for (int t = 0; t < 8; ++t) {
            int k = kb + 64 * (t & 3);
            int r0 = rq + 16 * (t >> 2);
            float g0 = gelu_exact(hb[(size_t)(r0 + 0) * H1 + k]);
            float g1 = gelu_exact(hb[(size_t)(r0 + 1) * H1 + k]);
            float g2 = gelu_exact(hb[(size_t)(r0 + 2) * H1 + k]);
            float g3 = gelu_exact(hb[(size_t)(r0 + 3) * H1 + k]);
            float4 v = make_float4(g0, g1, g2, g3);
            *(float4*)&hsT[k][r0] = v;
        }
    }
    __syncthreads();

    const int col = tid & 31;
    const int rg = (tid >> 5) * 4;  // 4 rows per thread
    float acc0 = 0.f, acc1 = 0.f, acc2 = 0.f, acc3 = 0.f;
    for (int k = 0; k < H1; ++k) {
        float w = w2s[k * DOUT + col];
        float4 hv = *(const float4*)&hsT[k][rg];
        acc0 = fmaf(hv.x, w, acc0);
        acc1 = fmaf(hv.y, w, acc1);
        acc2 = fmaf(hv.z, w, acc2);
        acc3 = fmaf(hv.w, w, acc3);
    }
    float bias = b2[col];
    const int rowg = blk * 32 + rg;
    feats[(size_t)(rowg + 0) * DOUT + col] = acc0 + bias;
    feats[(size_t)(rowg + 1) * DOUT + col] = acc1 + bias;
    feats[(size_t)(rowg + 2) * DOUT + col] = acc2 + bias;
    feats[(size_t)(rowg + 3) * DOUT + col] = acc3 + bias;
}

// ---------------- Ward clustering (R5 structure: u32-DPP argmin, prefetched centroids, alive mask) ----------------
__global__ __launch_bounds__(256) void ward_kernel(const float* __restrict__ feats,
                                                   int* __restrict__ out) {
    __shared__ __align__(16) float cost[NPTS * RSTR];  // full matrix
    __shared__ float centsT[32 * CSTR];                // [d][r]
    __shared__ unsigned long long rowkey[NPTS];
    __shared__ float sqArr[NPTS];
    __shared__ float szsE[NPTS];
    __shared__ int rnk[NPTS];

    const int b = blockIdx.x;
    const int tid = threadIdx.x;
    const float* f = feats + (size_t)b * NPTS * DOUT;
    const float INF = __builtin_inff();

    // ---- init (all 4 waves) ----
    for (int i = tid; i < NPTS * DOUT; i += 256) {
        int r = i >> 5, d = i & 31;
        centsT[d * CSTR + r] = f[i];
    }
    __syncthreads();
    if (tid < NPTS) {
        float s = 0.f;
#pragma unroll
        for (int d = 0; d < 32; ++d) {
            float v = centsT[d * CSTR + tid];
            s = fmaf(v, v, s);
        }
        sqArr[tid] = s;
    }
    __syncthreads();
    {
        int ti = tid >> 4, tj = tid & 15;
        int I0 = ti * 8, J0 = tj * 8;
        float acc[8][8];
#pragma unroll
        for (int u = 0; u < 8; ++u)
#pragma unroll
            for (int v = 0; v < 8; ++v) acc[u][v] = 0.f;
        for (int d = 0; d < 32; ++d) {
            float a[8], bb[8];
#pragma unroll
            for (int u = 0; u < 8; ++u) a[u] = centsT[d * CSTR + I0 + u];
#pragma unroll
            for (int v = 0; v < 8; ++v) bb[v] = centsT[d * CSTR + J0 + v];
#pragma unroll
            for (int u = 0; u < 8; ++u)
#pragma unroll
                for (int v = 0; v < 8; ++v)
                    acc[u][v] = fmaf(a[u], bb[v], acc[u][v]);
        }
#pragma unroll
        for (int u = 0; u < 8; ++u) {
#pragma unroll
            for (int v = 0; v < 8; ++v) {
                int i = I0 + u, j = J0 + v;
                float d2 = sqArr[i] + sqArr[j] - 2.0f * acc[u][v];
                if (d2 < 0.f) d2 = 0.f;
                float w = (1.0f * 1.0f) / (1.0f + 1.0f + 1e-30f);
                cost[i * RSTR + j] = (i == j) ? INF : w * d2;
            }
        }
    }
    __syncthreads();
    if (tid < NPTS) {
        unsigned long long best = DEADKEY;
        for (int j = 0; j < NPTS; ++j) {
            float v = cost[tid * RSTR + j];
            unsigned long long k = mkkey(v, tid, j);
            if (k < best) best = k;
        }
        rowkey[tid] = best;
    }
    __syncthreads();

    if (tid >= 64) return;  // wave 0 only
    const int lane = tid;
    const int hh = lane & 31;
    const int r0 = lane * 2, r1 = lane * 2 + 1;

    unsigned long long k0 = rowkey[r0], k1 = rowkey[r1];
    float q0 = sqArr[r0], q1 = sqArr[r1];
    float s0 = 1.0f, s1 = 1.0f;
    int lab0 = r0, lab1 = r1;
    unsigned long long alive0 = ~0ull, alive1 = ~0ull;

    float2 pref[32];
#pragma unroll
    for (int d = 0; d < 32; ++d) pref[d] = *(const float2*)&centsT[d * CSTR + r0];

    for (int it = 0; it < NPTS - KCL; ++it) {
        // P1: global argmin via u32-bits DPP min + ballot (exact flat-index tie-break)
        unsigned bv0 = (unsigned)(k0 >> 32), bv1 = (unsigned)(k1 >> 32);
        unsigned lmin = bv0 < bv1 ? bv0 : bv1;
        unsigned lflat = (bv0 <= bv1) ? (unsigned)(k0 & 0x3FFFu) : (unsigned)(k1 & 0x3FFFu);
        unsigned gmin = wave_umin_bcast(lmin);
        unsigned long long bmask = __ballot(lmin == gmin);
        int lsel = __ffsll(bmask) - 1;
        unsigned flat = (unsigned)__builtin_amdgcn_readlane((int)lflat, lsel);
        int ra = (int)(flat >> 7), ca = (int)(flat & 127u);
        const int i2 = ra < ca ? ra : ca;
        const int j2 = ra < ca ? ca : ra;

        float si = readlanef((i2 & 1) ? s1 : s0, i2 >> 1);
        float sj = readlanef((j2 & 1) ? s1 : s0, j2 >> 1);
        const float snew = si + sj;

        int arg0 = (int)(k0 & 127u), arg1 = (int)(k1 & 127u);
        bool d0 = (s0 > 0.f) && r0 != i2 && r0 != j2 && (arg0 == i2 || arg0 == j2);
        bool d1 = (s1 > 0.f) && r1 != i2 && r1 != j2 && (arg1 == i2 || arg1 == j2);
        unsigned long long m0 = __ballot(d0), m1 = __ballot(d1);

        // P3: merge centroid (lanes<32 = dim d), update scalar state
        float newc = 0.f;
        if (lane < 32) {
            float ci = centsT[lane * CSTR + i2];
            float cj = centsT[lane * CSTR + j2];
            newc = (ci * si + cj * sj) / (si + sj);
            centsT[lane * CSTR + i2] = newc;
        }
        if (lab0 == j2) lab0 = i2;
        if (lab1 == j2) lab1 = i2;
        if (r0 == i2) s0 = snew; else if (r0 == j2) { s0 = 0.f; k0 = DEADKEY; }
        if (r1 == i2) s1 = snew; else if (r1 == j2) { s1 = 0.f; k1 = DEADKEY; }
        if (j2 < 64) alive0 &= ~(1ull << j2); else alive1 &= ~(1ull << (j2 - 64));

        // broadcast merged centroid to all lanes
        float c2[32];
#pragma unroll
        for (int d = 0; d < 32; ++d) c2[d] = readlanef(newc, d);

        // P4: pure-VALU dots from prefetched registers
        float qn = 0.f, dot0 = 0.f, dot1 = 0.f;
#pragma unroll
        for (int d = 0; d < 32; ++d) {
            float cc = c2[d];
            qn = fmaf(cc, cc, qn);
            dot0 = fmaf(pref[d].x, cc, dot0);
            dot1 = fmaf(pref[d].y, cc, dot1);
        }
        if (r0 == i2) q0 = qn;
        if (r1 == i2) q1 = qn;
        bool w0 = (s0 > 0.f) && r0 != i2 && r0 != j2;
        bool w1 = (s1 > 0.f) && r1 != i2 && r1 != j2;
        unsigned cb0 = 0xFFFFFFFFu, cb1 = 0xFFFFFFFFu;
        if (w0) {
            float d2 = q0 + qn - 2.0f * dot0;
            if (d2 < 0.f) d2 = 0.f;
            float w = (s0 * snew) / (s0 + snew + 1e-30f);
            float v0 = w * d2;
            cost[r0 * RSTR + i2] = v0;
            cost[i2 * RSTR + r0] = v0;
            cb0 = __float_as_uint(v0);
            if (!d0) {
                unsigned long long nk = mkkey(v0, r0, i2);
                if (nk < k0) k0 = nk;
            }
        }
        if (w1) {
            float d2 = q1 + qn - 2.0f * dot1;
            if (d2 < 0.f) d2 = 0.f;
            float w = (s1 * snew) / (s1 + snew + 1e-30f);
            float v1 = w * d2;
            cost[r1 * RSTR + i2] = v1;
            cost[i2 * RSTR + r1] = v1;
            cb1 = __float_as_uint(v1);
            if (!d1) {
                unsigned long long nk = mkkey(v1, r1, i2);
                if (nk < k1) k1 = nk;
            }
        }
        // row i2's exact new key from the fresh values (u32 reduce)
        {
            unsigned lm = cb0 < cb1 ? cb0 : cb1;
            int lcol = (cb0 <= cb1) ? r0 : r1;
            unsigned gm = wave_umin_bcast(lm);
            unsigned long long mk2 = __ballot(lm == gm);
            int ls = __ffsll(mk2) - 1;
            int col = __builtin_amdgcn_readlane(lcol, ls);
            unsigned long long ki2 = ((unsigned long long)gm << 32) | (unsigned)((i2 << 7) | col);
            if (r0 == i2) k0 = ki2;
            if (r1 == i2) k1 = ki2;
        }

        // P6: dirty-row rescans (2 rows/round, b128 + alive-mask + u32 half-min)
        unsigned long long mm0 = m0, mm1 = m1;
        while (mm0 | mm1) {
            int rA, rB;
            bool hasB = false;
            if (mm0) { int t = __ffsll(mm0) - 1; rA = 2 * t; mm0 &= mm0 - 1; }
            else     { int t = __ffsll(mm1) - 1; rA = 2 * t + 1; mm1 &= mm1 - 1; }
            if (mm0) { int t = __ffsll(mm0) - 1; rB = 2 * t; mm0 &= mm0 - 1; hasB = true; }
            else if (mm1) { int t = __ffsll(mm1) - 1; rB = 2 * t + 1; mm1 &= mm1 - 1; hasB = true; }
            else rB = rA;

            int r = (lane < 32) ? rA : rB;
            float4 cv = *(const float4*)&cost[r * RSTR + 4 * hh];
            unsigned long long word = (hh < 16) ? alive0 : alive1;
            unsigned nib = (unsigned)(word >> ((4 * hh) & 63)) & 0xFu;
            unsigned e0 = (nib & 1u) ? __float_as_uint(cv.x) : 0xFFFFFFFFu;
            unsigned e1 = (nib & 2u) ? __float_as_uint(cv.y) : 0xFFFFFFFFu;
            unsigned e2 = (nib & 4u) ? __float_as_uint(cv.z) : 0xFFFFFFFFu;
            unsigned e3 = (nib & 8u) ? __float_as_uint(cv.w) : 0xFFFFFFFFu;
            unsigned m = e0; int c = 0;
            if (e1 < m) { m = e1; c = 1; }
            if (e2 < m) { m = e2; c = 2; }
            if (e3 < m) { m = e3; c = 3; }
            int lcol = 4 * hh + c;
            unsigned hm = half_umin(m);
            unsigned vA = (unsigned)__builtin_amdgcn_readlane((int)hm, 31);
            unsigned vB = (unsigned)__builtin_amdgcn_readlane((int)hm, 63);
            unsigned vref = (lane < 32) ? vA : vB;
            unsigned long long msk = __ballot(m == vref);
            int laneA = __ffsll(msk & 0xFFFFFFFFull) - 1;
            int laneB = 32 + __ffsll(msk >> 32) - 1;
            int colA = __builtin_amdgcn_readlane(lcol, laneA);
            int colB = __builtin_amdgcn_readlane(lcol, laneB);
            unsigned long long keyA = ((unsigned long long)vA << 32) | (unsigned)((rA << 7) | colA);
            unsigned long long keyB = ((unsigned long long)vB << 32) | (unsigned)((rB << 7) | colB);
            if (lane == (rA >> 1)) { if (rA & 1) k1 = keyA; else k0 = keyA; }
            if (hasB && lane == (rB >> 1)) { if (rB & 1) k1 = keyB; else k0 = keyB; }
        }

        // prefetch next iteration's own-row centroids
#pragma unroll
        for (int d = 0; d < 32; ++d) pref[d] = *(const float2*)&centsT[d * CSTR + r0];
    }

    // final relabel
    szsE[r0] = s0;
    szsE[r1] = s1;
    __asm__ volatile("s_waitcnt lgkmcnt(0)" ::: "memory");
    if (lane == 0) {
        int c = 0;
        for (int i = 0; i < NPTS; ++i) rnk[i] = (szsE[i] > 0.f) ? c++ : -1;
    }
    __asm__ volatile("s_waitcnt lgkmcnt(0)" ::: "memory");
    out[b * NPTS + r0] = rnk[lab0];
    out[b * NPTS + r1] = rnk[lab1];
}

extern "C" void kernel_launch(void* const* d_in, const int* in_sizes, int n_in,
                              void* d_out, int out_size, void* d_ws, size_t ws_size,
                              hipStream_t stream) {
    const float* x  = (const float*)d_in[0];
    const float* W1 = (const float*)d_in[1];
    const float* b1 = (const float*)d_in[2];
    const float* W2 = (const float*)d_in[3];
    const float* b2 = (const float*)d_in[4];

    float* h = (float*)d_ws;
    float* feats = h + (size_t)MROWS * H1;
    int* out = (int*)d_out;

    mlp1_kernel<<<dim3(MROWS / 128, H1 / 128), 256, 0, stream>>>(x, W1, b1, h);
    mlp2_kernel<<<MROWS / 32, 256, 0, stream>>>(h, W2, b2, feats);
    ward_kernel<<<BB, 256, 0, stream>>>(feats, out);
}

// Round 8
// 492.228 us; speedup vs baseline: 1.0990x; 1.0990x over previous
//
#include <hip/hip_runtime.h>
#include <math.h>

#define BB 128
#define NN 128
#define DIN 1024
#define H1 256
#define DOUT 32
#define KCL 8
#define NPTS 128
#define MROWS (BB*NN)   // 16384
#define CSTR 130        // centsT row stride (words)
#define RSTR 132        // cost row stride (words, 16B aligned)
#define DEADKEY 0xFFFFFFFF00000000ull

__device__ __forceinline__ float gelu_exact(float v) {
    return 0.5f * v * (1.0f + erff(v * 0.70710678118654752f));
}

__device__ __forceinline__ unsigned long long mkkey(float v, int r, int j) {
    return ((unsigned long long)__float_as_uint(v) << 32) | (unsigned)((r << 7) | j);
}

__device__ __forceinline__ float readlanef(float v, int lane) {
    return __int_as_float(__builtin_amdgcn_readlane(__float_as_int(v), lane));
}

// u32 min via DPP (costs are >=0 floats: IEEE order == unsigned bit order)
template<int CTRL, int RMASK>
__device__ __forceinline__ unsigned dpp_umin_step(unsigned v) {
    unsigned t = (unsigned)__builtin_amdgcn_update_dpp((int)v, (int)v, CTRL, RMASK, 0xf, false);
    return t < v ? t : v;
}
__device__ __forceinline__ unsigned wave_umin_bcast(unsigned v) {
    v = dpp_umin_step<0x111, 0xf>(v);
    v = dpp_umin_step<0x112, 0xf>(v);
    v = dpp_umin_step<0x114, 0xf>(v);
    v = dpp_umin_step<0x118, 0xf>(v);
    v = dpp_umin_step<0x142, 0xa>(v);
    v = dpp_umin_step<0x143, 0xc>(v);
    return (unsigned)__builtin_amdgcn_readlane((int)v, 63);
}
// lane31 = min(lanes0..31), lane63 = min(lanes32..63)
__device__ __forceinline__ unsigned half_umin(unsigned v) {
    v = dpp_umin_step<0x111, 0xf>(v);
    v = dpp_umin_step<0x112, 0xf>(v);
    v = dpp_umin_step<0x114, 0xf>(v);
    v = dpp_umin_step<0x118, 0xf>(v);
    v = dpp_umin_step<0x142, 0xa>(v);
    return v;
}

// ---------------- GEMM1: h = gelu(x) @ W1 + b1 ----------------
// 64x128 tile, 256 threads, 4x(4+4) microtile, BK=32, double-buffered LDS,
// reg prefetch, one barrier per K-tile. Grid 512 -> 2 blocks/CU (8 waves/CU).
// All LDS fragment reads stride-4 => <=2 lanes/bank-class (conflict-free).
__global__ __launch_bounds__(256) void mlp1_kernel(const float* __restrict__ x,
                                                   const float* __restrict__ W1,
                                                   const float* __restrict__ b1,
                                                   float* __restrict__ h) {
    __shared__ float As[2][32][68];   // [buf][k][m]  17.4 KB
    __shared__ float Bs[2][32][132];  // [buf][k][n]  33.8 KB
    const int bm = blockIdx.x;    // 256 row-tiles of 64
    const int bn = blockIdx.y;    // 2 col-tiles of 128
    const int tid = threadIdx.x;
    const int tx = tid & 15, ty = tid >> 4;

    float acc[4][8];
#pragma unroll
    for (int i = 0; i < 4; ++i)
#pragma unroll
        for (int j = 0; j < 8; ++j) acc[i][j] = 0.f;

    // staging indices
    const int arow = tid >> 2;          // 0..63
    const int ak8 = (tid & 3) * 8;      // k offset 0,8,16,24
    const int bk = tid >> 3;            // 0..31
    const int bc16 = (tid & 7) * 16;    // 0..112

    const float* xrow = x + (size_t)(bm * 64 + arow) * DIN;
    const float* wbase = W1 + bn * 128;

    float4 av0 = *(const float4*)(xrow + ak8);
    float4 av1 = *(const float4*)(xrow + ak8 + 4);
    float4 wv[4];
#pragma unroll
    for (int i = 0; i < 4; ++i)
        wv[i] = *(const float4*)(wbase + (size_t)bk * H1 + bc16 + 4 * i);

    for (int t = 0; t < 32; ++t) {
        const int p = t & 1;
        As[p][ak8 + 0][arow] = gelu_exact(av0.x);
        As[p][ak8 + 1][arow] = gelu_exact(av0.y);
        As[p][ak8 + 2][arow] = gelu_exact(av0.z);
        As[p][ak8 + 3][arow] = gelu_exact(av0.w);
        As[p][ak8 + 4][arow] = gelu_exact(av1.x);
        As[p][ak8 + 5][arow] = gelu_exact(av1.y);
        As[p][ak8 + 6][arow] = gelu_exact(av1.z);
        As[p][ak8 + 7][arow] = gelu_exact(av1.w);
#pragma unroll
        for (int i = 0; i < 4; ++i)
            *(float4*)&Bs[p][bk][bc16 + 4 * i] = wv[i];
        if (t + 1 < 32) {
            const int kt = (t + 1) * 32;
            av0 = *(const float4*)(xrow + kt + ak8);
            av1 = *(const float4*)(xrow + kt + ak8 + 4);
#pragma unroll
            for (int i = 0; i < 4; ++i)
                wv[i] = *(const float4*)(wbase + (size_t)(kt + bk) * H1 + bc16 + 4 * i);
        }
        __syncthreads();
#pragma unroll
        for (int kk = 0; kk < 32; ++kk) {
            float a[4], b[8];
            *(float4*)&a[0] = *(const float4*)&As[p][kk][ty * 4];
            *(float4*)&b[0] = *(const float4*)&Bs[p][kk][tx * 4];
            *(float4*)&b[4] = *(const float4*)&Bs[p][kk][64 + tx * 4];
#pragma unroll
            for (int i = 0; i < 4; ++i)
#pragma unroll
                for (int j = 0; j < 8; ++j)
                    acc[i][j] = fmaf(a[i], b[j], acc[i][j]);
        }
    }

    const int row = bm * 64 + ty * 4;
    const int col = bn * 128 + tx * 4;
    float4 bias0 = *(const float4*)(b1 + col);
    float4 bias1 = *(const float4*)(b1 + col + 64);
#pragma unroll
    for (int i = 0; i < 4; ++i) {
        float4 o0, o1;
        o0.x = acc[i][0] + bias0.x;
        o0.y = acc[i][1] + bias0.y;
        o0.z = acc[i][2] + bias0.z;
        o0.w = acc[i][3] + bias0.w;
        o1.x = acc[i][4] + bias1.x;
        o1.y = acc[i][5] + bias1.y;
        o1.z = acc[i][6] + bias1.z;
        o1.w = acc[i][7] + bias1.w;
        *(float4*)(h + (size_t)(row + i) * H1 + col) = o0;
        *(float4*)(h + (size_t)(row + i) * H1 + col + 64) = o1;
    }
}

// ---------------- GEMM2: feats = gelu(h) @ W2 + b2 (best-measured R4 version) ----------------
__global__ __launch_bounds__(256) void mlp2_kernel(const float* __restrict__ h,
                                                   const float* __restrict__ W2,
                                                   const float* __restrict__ b2,
                                                   float* __restrict__ feats) {
    __shared__ float hs[16][257];
    __shared__ float w2s[H1 * DOUT];
    const int blk = blockIdx.x;
    const int tid = threadIdx.x;

    for (int i = tid; i < (H1 * DOUT) / 4; i += 256) {
        ((float4*)w2s)[i] = ((const float4*)W2)[i];
    }
    const float* hb = h + (size_t)blk * 16 * H1;
    for (int i = tid; i < (16 * H1) / 4; i += 256) {
        float4 v = ((const float4*)hb)[i];
        int r = i >> 6;
        int c = (i & 63) * 4;
        hs[r][c + 0] = gelu_exact(v.x);
        hs[r][c + 1] = gelu_exact(v.y);
        hs[r][c + 2] = gelu_exact(v.z);
        hs[r][c + 3] = gelu_exact(v.w);
    }
    __syncthreads();

    const int col = tid & 31;
    const int r0 = (tid >> 5) * 2;
    float acc0 = 0.f, acc1 = 0.f;
    for (int k = 0; k < H1; ++k) {
        float w = w2s[k * DOUT + col];
        acc0 = fmaf(hs[r0 + 0][k], w, acc0);
        acc1 = fmaf(hs[r0 + 1][k], w, acc1);
    }
    float bias = b2[col];
    const int rowg = blk * 16 + r0;
    feats[(size_t)(rowg + 0) * DOUT + col] = acc0 + bias;
    feats[(size_t)(rowg + 1) * DOUT + col] = acc1 + bias;
}

// ---------------- Ward clustering (R5 best-measured version, verbatim) ----------------
__global__ __launch_bounds__(256) void ward_kernel(const float* __restrict__ feats,
                                                   int* __restrict__ out) {
    __shared__ __align__(16) float cost[NPTS * RSTR];  // full matrix
    __shared__ float centsT[32 * CSTR];                // [d][r]
    __shared__ unsigned long long rowkey[NPTS];
    __shared__ float sqArr[NPTS];
    __shared__ float szsE[NPTS];
    __shared__ int rnk[NPTS];

    const int b = blockIdx.x;
    const int tid = threadIdx.x;
    const float* f = feats + (size_t)b * NPTS * DOUT;
    const float INF = __builtin_inff();

    for (int i = tid; i < NPTS * DOUT; i += 256) {
        int r = i >> 5, d = i & 31;
        centsT[d * CSTR + r] = f[i];
    }
    __syncthreads();
    if (tid < NPTS) {
        float s = 0.f;
#pragma unroll
        for (int d = 0; d < 32; ++d) {
            float v = centsT[d * CSTR + tid];
            s = fmaf(v, v, s);
        }
        sqArr[tid] = s;
    }
    __syncthreads();
    {
        int ti = tid >> 4, tj = tid & 15;
        int I0 = ti * 8, J0 = tj * 8;
        float acc[8][8];
#pragma unroll
        for (int u = 0; u < 8; ++u)
#pragma unroll
            for (int v = 0; v < 8; ++v) acc[u][v] = 0.f;
        for (int d = 0; d < 32; ++d) {
            float a[8], bb[8];
#pragma unroll
            for (int u = 0; u < 8; ++u) a[u] = centsT[d * CSTR + I0 + u];
#pragma unroll
            for (int v = 0; v < 8; ++v) bb[v] = centsT[d * CSTR + J0 + v];
#pragma unroll
            for (int u = 0; u < 8; ++u)
#pragma unroll
                for (int v = 0; v < 8; ++v)
                    acc[u][v] = fmaf(a[u], bb[v], acc[u][v]);
        }
#pragma unroll
        for (int u = 0; u < 8; ++u) {
#pragma unroll
            for (int v = 0; v < 8; ++v) {
                int i = I0 + u, j = J0 + v;
                float d2 = sqArr[i] + sqArr[j] - 2.0f * acc[u][v];
                if (d2 < 0.f) d2 = 0.f;
                float w = (1.0f * 1.0f) / (1.0f + 1.0f + 1e-30f);
                cost[i * RSTR + j] = (i == j) ? INF : w * d2;
            }
        }
    }
    __syncthreads();
    if (tid < NPTS) {
        unsigned long long best = DEADKEY;
        for (int j = 0; j < NPTS; ++j) {
            float v = cost[tid * RSTR + j];
            unsigned long long k = mkkey(v, tid, j);
            if (k < best) best = k;
        }
        rowkey[tid] = best;
    }
    __syncthreads();

    if (tid >= 64) return;  // wave 0 only
    const int lane = tid;
    const int hh = lane & 31;
    const int r0 = lane * 2, r1 = lane * 2 + 1;

    unsigned long long k0 = rowkey[r0], k1 = rowkey[r1];
    float q0 = sqArr[r0], q1 = sqArr[r1];
    float s0 = 1.0f, s1 = 1.0f;
    int lab0 = r0, lab1 = r1;
    unsigned long long alive0 = ~0ull, alive1 = ~0ull;

    float2 pref[32];
#pragma unroll
    for (int d = 0; d < 32; ++d) pref[d] = *(const float2*)&centsT[d * CSTR + r0];

    for (int it = 0; it < NPTS - KCL; ++it) {
        unsigned bv0 = (unsigned)(k0 >> 32), bv1 = (unsigned)(k1 >> 32);
        unsigned lmin = bv0 < bv1 ? bv0 : bv1;
        unsigned lflat = (bv0 <= bv1) ? (unsigned)(k0 & 0x3FFFu) : (unsigned)(k1 & 0x3FFFu);
        unsigned gmin = wave_umin_bcast(lmin);
        unsigned long long bmask = __ballot(lmin == gmin);
        int lsel = __ffsll(bmask) - 1;
        unsigned flat = (unsigned)__builtin_amdgcn_readlane((int)lflat, lsel);
        int ra = (int)(flat >> 7), ca = (int)(flat & 127u);
        const int i2 = ra < ca ? ra : ca;
        const int j2 = ra < ca ? ca : ra;

        float si = readlanef((i2 & 1) ? s1 : s0, i2 >> 1);
        float sj = readlanef((j2 & 1) ? s1 : s0, j2 >> 1);
        const float snew = si + sj;

        int arg0 = (int)(k0 & 127u), arg1 = (int)(k1 & 127u);
        bool d0 = (s0 > 0.f) && r0 != i2 && r0 != j2 && (arg0 == i2 || arg0 == j2);
        bool d1 = (s1 > 0.f) && r1 != i2 && r1 != j2 && (arg1 == i2 || arg1 == j2);
        unsigned long long m0 = __ballot(d0), m1 = __ballot(d1);

        float newc = 0.f;
        if (lane < 32) {
            float ci = centsT[lane * CSTR + i2];
            float cj = centsT[lane * CSTR + j2];
            newc = (ci * si + cj * sj) / (si + sj);
            centsT[lane * CSTR + i2] = newc;
        }
        if (lab0 == j2) lab0 = i2;
        if (lab1 == j2) lab1 = i2;
        if (r0 == i2) s0 = snew; else if (r0 == j2) { s0 = 0.f; k0 = DEADKEY; }
        if (r1 == i2) s1 = snew; else if (r1 == j2) { s1 = 0.f; k1 = DEADKEY; }
        if (j2 < 64) alive0 &= ~(1ull << j2); else alive1 &= ~(1ull << (j2 - 64));

        float c2[32];
#pragma unroll
        for (int d = 0; d < 32; ++d) c2[d] = readlanef(newc, d);

        float qn = 0.f, dot0 = 0.f, dot1 = 0.f;
#pragma unroll
        for (int d = 0; d < 32; ++d) {
            float cc = c2[d];
            qn = fmaf(cc, cc, qn);
            dot0 = fmaf(pref[d].x, cc, dot0);
            dot1 = fmaf(pref[d].y, cc, dot1);
        }
        if (r0 == i2) q0 = qn;
        if (r1 == i2) q1 = qn;
        bool w0 = (s0 > 0.f) && r0 != i2 && r0 != j2;
        bool w1 = (s1 > 0.f) && r1 != i2 && r1 != j2;
        unsigned cb0 = 0xFFFFFFFFu, cb1 = 0xFFFFFFFFu;
        if (w0) {
            float d2 = q0 + qn - 2.0f * dot0;
            if (d2 < 0.f) d2 = 0.f;
            float w = (s0 * snew) / (s0 + snew + 1e-30f);
            float v0 = w * d2;
            cost[r0 * RSTR + i2] = v0;
            cost[i2 * RSTR + r0] = v0;
            cb0 = __float_as_uint(v0);
            if (!d0) {
                unsigned long long nk = mkkey(v0, r0, i2);
                if (nk < k0) k0 = nk;
            }
        }
        if (w1) {
            float d2 = q1 + qn - 2.0f * dot1;
            if (d2 < 0.f) d2 = 0.f;
            float w = (s1 * snew) / (s1 + snew + 1e-30f);
            float v1 = w * d2;
            cost[r1 * RSTR + i2] = v1;
            cost[i2 * RSTR + r1] = v1;
            cb1 = __float_as_uint(v1);
            if (!d1) {
                unsigned long long nk = mkkey(v1, r1, i2);
                if (nk < k1) k1 = nk;
            }
        }
        {
            unsigned lm = cb0 < cb1 ? cb0 : cb1;
            int lcol = (cb0 <= cb1) ? r0 : r1;
            unsigned gm = wave_umin_bcast(lm);
            unsigned long long mk2 = __ballot(lm == gm);
            int ls = __ffsll(mk2) - 1;
            int col = __builtin_amdgcn_readlane(lcol, ls);
            unsigned long long ki2 = ((unsigned long long)gm << 32) | (unsigned)((i2 << 7) | col);
            if (r0 == i2) k0 = ki2;
            if (r1 == i2) k1 = ki2;
        }

        unsigned long long mm0 = m0, mm1 = m1;
        while (mm0 | mm1) {
            int rA, rB;
            bool hasB = false;
            if (mm0) { int t = __ffsll(mm0) - 1; rA = 2 * t; mm0 &= mm0 - 1; }
            else     { int t = __ffsll(mm1) - 1; rA = 2 * t + 1; mm1 &= mm1 - 1; }
            if (mm0) { int t = __ffsll(mm0) - 1; rB = 2 * t; mm0 &= mm0 - 1; hasB = true; }
            else if (mm1) { int t = __ffsll(mm1) - 1; rB = 2 * t + 1; mm1 &= mm1 - 1; hasB = true; }
            else rB = rA;

            int r = (lane < 32) ? rA : rB;
            float4 cv = *(const float4*)&cost[r * RSTR + 4 * hh];
            unsigned long long word = (hh < 16) ? alive0 : alive1;
            unsigned nib = (unsigned)(word >> ((4 * hh) & 63)) & 0xFu;
            unsigned e0 = (nib & 1u) ? __float_as_uint(cv.x) : 0xFFFFFFFFu;
            unsigned e1 = (nib & 2u) ? __float_as_uint(cv.y) : 0xFFFFFFFFu;
            unsigned e2 = (nib & 4u) ? __float_as_uint(cv.z) : 0xFFFFFFFFu;
            unsigned e3 = (nib & 8u) ? __float_as_uint(cv.w) : 0xFFFFFFFFu;
            unsigned m = e0; int c = 0;
            if (e1 < m) { m = e1; c = 1; }
            if (e2 < m) { m = e2; c = 2; }
            if (e3 < m) { m = e3; c = 3; }
            int lcol = 4 * hh + c;
            unsigned hm = half_umin(m);
            unsigned vA = (unsigned)__builtin_amdgcn_readlane((int)hm, 31);
            unsigned vB = (unsigned)__builtin_amdgcn_readlane((int)hm, 63);
            unsigned vref = (lane < 32) ? vA : vB;
            unsigned long long msk = __ballot(m == vref);
            int laneA = __ffsll(msk & 0xFFFFFFFFull) - 1;
            int laneB = 32 + __ffsll(msk >> 32) - 1;
            int colA = __builtin_amdgcn_readlane(lcol, laneA);
            int colB = __builtin_amdgcn_readlane(lcol, laneB);
            unsigned long long keyA = ((unsigned long long)vA << 32) | (unsigned)((rA << 7) | colA);
            unsigned long long keyB = ((unsigned long long)vB << 32) | (unsigned)((rB << 7) | colB);
            if (lane == (rA >> 1)) { if (rA & 1) k1 = keyA; else k0 = keyA; }
            if (hasB && lane == (rB >> 1)) { if (rB & 1) k1 = keyB; else k0 = keyB; }
        }

#pragma unroll
        for (int d = 0; d < 32; ++d) pref[d] = *(const float2*)&centsT[d * CSTR + r0];
    }

    szsE[r0] = s0;
    szsE[r1] = s1;
    __asm__ volatile("s_waitcnt lgkmcnt(0)" ::: "memory");
    if (lane == 0) {
        int c = 0;
        for (int i = 0; i < NPTS; ++i) rnk[i] = (szsE[i] > 0.f) ? c++ : -1;
    }
    __asm__ volatile("s_waitcnt lgkmcnt(0)" ::: "memory");
    out[b * NPTS + r0] = rnk[lab0];
    out[b * NPTS + r1] = rnk[lab1];
}

extern "C" void kernel_launch(void* const* d_in, const int* in_sizes, int n_in,
                              void* d_out, int out_size, void* d_ws, size_t ws_size,
                              hipStream_t stream) {
    const float* x  = (const float*)d_in[0];
    const float* W1 = (const float*)d_in[1];
    const float* b1 = (const float*)d_in[2];
    const float* W2 = (const float*)d_in[3];
    const float* b2 = (const float*)d_in[4];

    float* h = (float*)d_ws;
    float* feats = h + (size_t)MROWS * H1;
    int* out = (int*)d_out;

    mlp1_kernel<<<dim3(MROWS / 64, H1 / 128), 256, 0, stream>>>(x, W1, b1, h);
    mlp2_kernel<<<MROWS / 16, 256, 0, stream>>>(h, W2, b2, feats);
    ward_kernel<<<BB, 256, 0, stream>>>(feats, out);
}

// Round 9
// 451.654 us; speedup vs baseline: 1.1977x; 1.0898x over previous
//
#include <hip/hip_runtime.h>
#include <math.h>

#define BB 128
#define NN 128
#define DIN 1024
#define H1 256
#define DOUT 32
#define KCL 8
#define NPTS 128
#define MROWS (BB*NN)   // 16384
#define CSTR 130        // centsT row stride (words, init staging only)
#define RSTR 132        // cost/G row stride (words, 16B aligned)
#define DEADKEY 0xFFFFFFFF00000000ull

__device__ __forceinline__ float gelu_exact(float v) {
    return 0.5f * v * (1.0f + erff(v * 0.70710678118654752f));
}

__device__ __forceinline__ unsigned long long mkkey(float v, int r, int j) {
    return ((unsigned long long)__float_as_uint(v) << 32) | (unsigned)((r << 7) | j);
}

__device__ __forceinline__ float readlanef(float v, int lane) {
    return __int_as_float(__builtin_amdgcn_readlane(__float_as_int(v), lane));
}

// u32 min via DPP (costs are >=0 floats: IEEE order == unsigned bit order)
template<int CTRL, int RMASK>
__device__ __forceinline__ unsigned dpp_umin_step(unsigned v) {
    unsigned t = (unsigned)__builtin_amdgcn_update_dpp((int)v, (int)v, CTRL, RMASK, 0xf, false);
    return t < v ? t : v;
}
__device__ __forceinline__ unsigned wave_umin_bcast(unsigned v) {
    v = dpp_umin_step<0x111, 0xf>(v);
    v = dpp_umin_step<0x112, 0xf>(v);
    v = dpp_umin_step<0x114, 0xf>(v);
    v = dpp_umin_step<0x118, 0xf>(v);
    v = dpp_umin_step<0x142, 0xa>(v);
    v = dpp_umin_step<0x143, 0xc>(v);
    return (unsigned)__builtin_amdgcn_readlane((int)v, 63);
}
// lane31 = min(lanes0..31), lane63 = min(lanes32..63)
__device__ __forceinline__ unsigned half_umin(unsigned v) {
    v = dpp_umin_step<0x111, 0xf>(v);
    v = dpp_umin_step<0x112, 0xf>(v);
    v = dpp_umin_step<0x114, 0xf>(v);
    v = dpp_umin_step<0x118, 0xf>(v);
    v = dpp_umin_step<0x142, 0xa>(v);
    return v;
}

// ---------------- GEMM1: h = gelu(x) @ W1 + b1 (best-measured R8 version) ----------------
__global__ __launch_bounds__(256) void mlp1_kernel(const float* __restrict__ x,
                                                   const float* __restrict__ W1,
                                                   const float* __restrict__ b1,
                                                   float* __restrict__ h) {
    __shared__ float As[2][32][68];   // [buf][k][m]
    __shared__ float Bs[2][32][132];  // [buf][k][n]
    const int bm = blockIdx.x;
    const int bn = blockIdx.y;
    const int tid = threadIdx.x;
    const int tx = tid & 15, ty = tid >> 4;

    float acc[4][8];
#pragma unroll
    for (int i = 0; i < 4; ++i)
#pragma unroll
        for (int j = 0; j < 8; ++j) acc[i][j] = 0.f;

    const int arow = tid >> 2;
    const int ak8 = (tid & 3) * 8;
    const int bk = tid >> 3;
    const int bc16 = (tid & 7) * 16;

    const float* xrow = x + (size_t)(bm * 64 + arow) * DIN;
    const float* wbase = W1 + bn * 128;

    float4 av0 = *(const float4*)(xrow + ak8);
    float4 av1 = *(const float4*)(xrow + ak8 + 4);
    float4 wv[4];
#pragma unroll
    for (int i = 0; i < 4; ++i)
        wv[i] = *(const float4*)(wbase + (size_t)bk * H1 + bc16 + 4 * i);

    for (int t = 0; t < 32; ++t) {
        const int p = t & 1;
        As[p][ak8 + 0][arow] = gelu_exact(av0.x);
        As[p][ak8 + 1][arow] = gelu_exact(av0.y);
        As[p][ak8 + 2][arow] = gelu_exact(av0.z);
        As[p][ak8 + 3][arow] = gelu_exact(av0.w);
        As[p][ak8 + 4][arow] = gelu_exact(av1.x);
        As[p][ak8 + 5][arow] = gelu_exact(av1.y);
        As[p][ak8 + 6][arow] = gelu_exact(av1.z);
        As[p][ak8 + 7][arow] = gelu_exact(av1.w);
#pragma unroll
        for (int i = 0; i < 4; ++i)
            *(float4*)&Bs[p][bk][bc16 + 4 * i] = wv[i];
        if (t + 1 < 32) {
            const int kt = (t + 1) * 32;
            av0 = *(const float4*)(xrow + kt + ak8);
            av1 = *(const float4*)(xrow + kt + ak8 + 4);
#pragma unroll
            for (int i = 0; i < 4; ++i)
                wv[i] = *(const float4*)(wbase + (size_t)(kt + bk) * H1 + bc16 + 4 * i);
        }
        __syncthreads();
#pragma unroll
        for (int kk = 0; kk < 32; ++kk) {
            float a[4], b[8];
            *(float4*)&a[0] = *(const float4*)&As[p][kk][ty * 4];
            *(float4*)&b[0] = *(const float4*)&Bs[p][kk][tx * 4];
            *(float4*)&b[4] = *(const float4*)&Bs[p][kk][64 + tx * 4];
#pragma unroll
            for (int i = 0; i < 4; ++i)
#pragma unroll
                for (int j = 0; j < 8; ++j)
                    acc[i][j] = fmaf(a[i], b[j], acc[i][j]);
        }
    }

    const int row = bm * 64 + ty * 4;
    const int col = bn * 128 + tx * 4;
    float4 bias0 = *(const float4*)(b1 + col);
    float4 bias1 = *(const float4*)(b1 + col + 64);
#pragma unroll
    for (int i = 0; i < 4; ++i) {
        float4 o0, o1;
        o0.x = acc[i][0] + bias0.x;
        o0.y = acc[i][1] + bias0.y;
        o0.z = acc[i][2] + bias0.z;
        o0.w = acc[i][3] + bias0.w;
        o1.x = acc[i][4] + bias1.x;
        o1.y = acc[i][5] + bias1.y;
        o1.z = acc[i][6] + bias1.z;
        o1.w = acc[i][7] + bias1.w;
        *(float4*)(h + (size_t)(row + i) * H1 + col) = o0;
        *(float4*)(h + (size_t)(row + i) * H1 + col + 64) = o1;
    }
}

// ---------------- GEMM2: feats = gelu(h) @ W2 + b2 (best-measured R4 version) ----------------
__global__ __launch_bounds__(256) void mlp2_kernel(const float* __restrict__ h,
                                                   const float* __restrict__ W2,
                                                   const float* __restrict__ b2,
                                                   float* __restrict__ feats) {
    __shared__ float hs[16][257];
    __shared__ float w2s[H1 * DOUT];
    const int blk = blockIdx.x;
    const int tid = threadIdx.x;

    for (int i = tid; i < (H1 * DOUT) / 4; i += 256) {
        ((float4*)w2s)[i] = ((const float4*)W2)[i];
    }
    const float* hb = h + (size_t)blk * 16 * H1;
    for (int i = tid; i < (16 * H1) / 4; i += 256) {
        float4 v = ((const float4*)hb)[i];
        int r = i >> 6;
        int c = (i & 63) * 4;
        hs[r][c + 0] = gelu_exact(v.x);
        hs[r][c + 1] = gelu_exact(v.y);
        hs[r][c + 2] = gelu_exact(v.z);
        hs[r][c + 3] = gelu_exact(v.w);
    }
    __syncthreads();

    const int col = tid & 31;
    const int r0 = (tid >> 5) * 2;
    float acc0 = 0.f, acc1 = 0.f;
    for (int k = 0; k < H1; ++k) {
        float w = w2s[k * DOUT + col];
        acc0 = fmaf(hs[r0 + 0][k], w, acc0);
        acc1 = fmaf(hs[r0 + 1][k], w, acc1);
    }
    float bias = b2[col];
    const int rowg = blk * 16 + r0;
    feats[(size_t)(rowg + 0) * DOUT + col] = acc0 + bias;
    feats[(size_t)(rowg + 1) * DOUT + col] = acc1 + bias;
}

// ---------------- Ward clustering: incremental Gram (no centroid recompute) ----------------
__global__ __launch_bounds__(256) void ward_kernel(const float* __restrict__ feats,
                                                   int* __restrict__ out) {
    __shared__ __align__(16) float cost[NPTS * RSTR];  // 67.6 KB
    __shared__ __align__(16) float G[NPTS * RSTR];     // 67.6 KB Gram matrix
    __shared__ float centsT[32 * CSTR];                // init staging only
    __shared__ unsigned long long rowkey[NPTS];
    __shared__ float sqArr[NPTS];
    __shared__ float szsE[NPTS];
    __shared__ int rnk[NPTS];

    const int b = blockIdx.x;
    const int tid = threadIdx.x;
    const float* f = feats + (size_t)b * NPTS * DOUT;
    const float INF = __builtin_inff();

    // ---- init (all 4 waves) ----
    for (int i = tid; i < NPTS * DOUT; i += 256) {
        int r = i >> 5, d = i & 31;
        centsT[d * CSTR + r] = f[i];
    }
    __syncthreads();
    if (tid < NPTS) {
        float s = 0.f;
#pragma unroll
        for (int d = 0; d < 32; ++d) {
            float v = centsT[d * CSTR + tid];
            s = fmaf(v, v, s);
        }
        sqArr[tid] = s;
    }
    __syncthreads();
    {
        int ti = tid >> 4, tj = tid & 15;
        int I0 = ti * 8, J0 = tj * 8;
        float acc[8][8];
#pragma unroll
        for (int u = 0; u < 8; ++u)
#pragma unroll
            for (int v = 0; v < 8; ++v) acc[u][v] = 0.f;
        for (int d = 0; d < 32; ++d) {
            float a[8], bb[8];
#pragma unroll
            for (int u = 0; u < 8; ++u) a[u] = centsT[d * CSTR + I0 + u];
#pragma unroll
            for (int v = 0; v < 8; ++v) bb[v] = centsT[d * CSTR + J0 + v];
#pragma unroll
            for (int u = 0; u < 8; ++u)
#pragma unroll
                for (int v = 0; v < 8; ++v)
                    acc[u][v] = fmaf(a[u], bb[v], acc[u][v]);
        }
#pragma unroll
        for (int u = 0; u < 8; ++u) {
#pragma unroll
            for (int v = 0; v < 8; ++v) {
                int i = I0 + u, j = J0 + v;
                G[i * RSTR + j] = acc[u][v];
                float d2 = sqArr[i] + sqArr[j] - 2.0f * acc[u][v];
                if (d2 < 0.f) d2 = 0.f;
                float w = (1.0f * 1.0f) / (1.0f + 1.0f + 1e-30f);
                cost[i * RSTR + j] = (i == j) ? INF : w * d2;
            }
        }
    }
    __syncthreads();
    if (tid < NPTS) {
        unsigned long long best = DEADKEY;
        for (int j = 0; j < NPTS; ++j) {
            float v = cost[tid * RSTR + j];
            unsigned long long k = mkkey(v, tid, j);
            if (k < best) best = k;
        }
        rowkey[tid] = best;
    }
    __syncthreads();

    if (tid >= 64) return;  // wave 0 only
    const int lane = tid;
    const int hh = lane & 31;
    const int r0 = lane * 2, r1 = lane * 2 + 1;

    unsigned long long k0 = rowkey[r0], k1 = rowkey[r1];
    float q0 = sqArr[r0], q1 = sqArr[r1];
    float s0 = 1.0f, s1 = 1.0f;
    int lab0 = r0, lab1 = r1;
    unsigned long long alive0 = ~0ull, alive1 = ~0ull;

    for (int it = 0; it < NPTS - KCL; ++it) {
        // P1: global argmin via u32-bits DPP min + ballot (exact flat-index tie-break)
        unsigned bv0 = (unsigned)(k0 >> 32), bv1 = (unsigned)(k1 >> 32);
        unsigned lmin = bv0 < bv1 ? bv0 : bv1;
        unsigned lflat = (bv0 <= bv1) ? (unsigned)(k0 & 0x3FFFu) : (unsigned)(k1 & 0x3FFFu);
        unsigned gmin = wave_umin_bcast(lmin);
        unsigned long long bmask = __ballot(lmin == gmin);
        int lsel = __ffsll(bmask) - 1;
        unsigned flat = (unsigned)__builtin_amdgcn_readlane((int)lflat, lsel);
        int ra = (int)(flat >> 7), ca = (int)(flat & 127u);
        const int i2 = ra < ca ? ra : ca;
        const int j2 = ra < ca ? ca : ra;

        // Gram rows i2, j2: issue immediately (only depend on i2/j2)
        float2 gi = *(const float2*)&G[i2 * RSTR + r0];
        float2 gj = *(const float2*)&G[j2 * RSTR + r0];

        float si = readlanef((i2 & 1) ? s1 : s0, i2 >> 1);
        float sj = readlanef((j2 & 1) ? s1 : s0, j2 >> 1);
        const float snew = si + sj;
        const float invs = 1.0f / snew;
        const float wa = si * invs, wb = sj * invs;

        int arg0 = (int)(k0 & 127u), arg1 = (int)(k1 & 127u);
        bool d0 = (s0 > 0.f) && r0 != i2 && r0 != j2 && (arg0 == i2 || arg0 == j2);
        bool d1 = (s1 > 0.f) && r1 != i2 && r1 != j2 && (arg1 == i2 || arg1 == j2);
        unsigned long long m0 = __ballot(d0), m1 = __ballot(d1);

        // scalar Gram entries for qn
        float Gii = readlanef((i2 & 1) ? gi.y : gi.x, i2 >> 1);
        float Gij = readlanef((i2 & 1) ? gj.y : gj.x, i2 >> 1);
        float Gjj = readlanef((j2 & 1) ? gj.y : gj.x, j2 >> 1);
        float dotA = wa * Gii + wb * Gij;   // dot(new, old_i2)
        float dotB = wa * Gij + wb * Gjj;   // dot(new, old_j2)
        float qn = wa * dotA + wb * dotB;   // dot(new, new)

        // per-lane dots with merged cluster (linear Gram update)
        float dot0 = wa * gi.x + wb * gj.x;
        float dot1 = wa * gi.y + wb * gj.y;

        // state updates
        if (lab0 == j2) lab0 = i2;
        if (lab1 == j2) lab1 = i2;
        if (r0 == i2) s0 = snew; else if (r0 == j2) { s0 = 0.f; k0 = DEADKEY; }
        if (r1 == i2) s1 = snew; else if (r1 == j2) { s1 = 0.f; k1 = DEADKEY; }
        if (j2 < 64) alive0 &= ~(1ull << j2); else alive1 &= ~(1ull << (j2 - 64));
        if (r0 == i2) { dot0 = qn; q0 = qn; }
        if (r1 == i2) { dot1 = qn; q1 = qn; }

        // G updates: row i2 (contiguous b64, conflict-free), column i2 (off-path)
        *(float2*)&G[i2 * RSTR + r0] = make_float2(dot0, dot1);
        G[r0 * RSTR + i2] = dot0;
        G[r1 * RSTR + i2] = dot1;

        // cost values for row/col i2
        bool w0 = (s0 > 0.f) && r0 != i2 && r0 != j2;
        bool w1 = (s1 > 0.f) && r1 != i2 && r1 != j2;
        unsigned cb0 = 0xFFFFFFFFu, cb1 = 0xFFFFFFFFu;
        if (w0) {
            float d2 = q0 + qn - 2.0f * dot0;
            if (d2 < 0.f) d2 = 0.f;
            float w = (s0 * snew) / (s0 + snew + 1e-30f);
            float v0 = w * d2;
            cost[r0 * RSTR + i2] = v0;
            cost[i2 * RSTR + r0] = v0;
            cb0 = __float_as_uint(v0);
            if (!d0) {
                unsigned long long nk = mkkey(v0, r0, i2);
                if (nk < k0) k0 = nk;
            }
        }
        if (w1) {
            float d2 = q1 + qn - 2.0f * dot1;
            if (d2 < 0.f) d2 = 0.f;
            float w = (s1 * snew) / (s1 + snew + 1e-30f);
            float v1 = w * d2;
            cost[r1 * RSTR + i2] = v1;
            cost[i2 * RSTR + r1] = v1;
            cb1 = __float_as_uint(v1);
            if (!d1) {
                unsigned long long nk = mkkey(v1, r1, i2);
                if (nk < k1) k1 = nk;
            }
        }
        // row i2's exact new key from the fresh values (u32 reduce)
        {
            unsigned lm = cb0 < cb1 ? cb0 : cb1;
            int lcol = (cb0 <= cb1) ? r0 : r1;
            unsigned gm = wave_umin_bcast(lm);
            unsigned long long mk2 = __ballot(lm == gm);
            int ls = __ffsll(mk2) - 1;
            int col = __builtin_amdgcn_readlane(lcol, ls);
            unsigned long long ki2 = ((unsigned long long)gm << 32) | (unsigned)((i2 << 7) | col);
            if (r0 == i2) k0 = ki2;
            if (r1 == i2) k1 = ki2;
        }

        // P6: dirty-row rescans (2 rows/round, b128 + alive-mask + u32 half-min)
        unsigned long long mm0 = m0, mm1 = m1;
        while (mm0 | mm1) {
            int rA, rB;
            bool hasB = false;
            if (mm0) { int t = __ffsll(mm0) - 1; rA = 2 * t; mm0 &= mm0 - 1; }
            else     { int t = __ffsll(mm1) - 1; rA = 2 * t + 1; mm1 &= mm1 - 1; }
            if (mm0) { int t = __ffsll(mm0) - 1; rB = 2 * t; mm0 &= mm0 - 1; hasB = true; }
            else if (mm1) { int t = __ffsll(mm1) - 1; rB = 2 * t + 1; mm1 &= mm1 - 1; hasB = true; }
            else rB = rA;

            int r = (lane < 32) ? rA : rB;
            float4 cv = *(const float4*)&cost[r * RSTR + 4 * hh];
            unsigned long long word = (hh < 16) ? alive0 : alive1;
            unsigned nib = (unsigned)(word >> ((4 * hh) & 63)) & 0xFu;
            unsigned e0 = (nib & 1u) ? __float_as_uint(cv.x) : 0xFFFFFFFFu;
            unsigned e1 = (nib & 2u) ? __float_as_uint(cv.y) : 0xFFFFFFFFu;
            unsigned e2 = (nib & 4u) ? __float_as_uint(cv.z) : 0xFFFFFFFFu;
            unsigned e3 = (nib & 8u) ? __float_as_uint(cv.w) : 0xFFFFFFFFu;
            unsigned m = e0; int c = 0;
            if (e1 < m) { m = e1; c = 1; }
            if (e2 < m) { m = e2; c = 2; }
            if (e3 < m) { m = e3; c = 3; }
            int lcol = 4 * hh + c;
            unsigned hm = half_umin(m);
            unsigned vA = (unsigned)__builtin_amdgcn_readlane((int)hm, 31);
            unsigned vB = (unsigned)__builtin_amdgcn_readlane((int)hm, 63);
            unsigned vref = (lane < 32) ? vA : vB;
            unsigned long long msk = __ballot(m == vref);
            int laneA = __ffsll(msk & 0xFFFFFFFFull) - 1;
            int laneB = 32 + __ffsll(msk >> 32) - 1;
            int colA = __builtin_amdgcn_readlane(lcol, laneA);
            int colB = __builtin_amdgcn_readlane(lcol, laneB);
            unsigned long long keyA = ((unsigned long long)vA << 32) | (unsigned)((rA << 7) | colA);
            unsigned long long keyB = ((unsigned long long)vB << 32) | (unsigned)((rB << 7) | colB);
            if (lane == (rA >> 1)) { if (rA & 1) k1 = keyA; else k0 = keyA; }
            if (hasB && lane == (rB >> 1)) { if (rB & 1) k1 = keyB; else k0 = keyB; }
        }
    }

    // final relabel
    szsE[r0] = s0;
    szsE[r1] = s1;
    __asm__ volatile("s_waitcnt lgkmcnt(0)" ::: "memory");
    if (lane == 0) {
        int c = 0;
        for (int i = 0; i < NPTS; ++i) rnk[i] = (szsE[i] > 0.f) ? c++ : -1;
    }
    __asm__ volatile("s_waitcnt lgkmcnt(0)" ::: "memory");
    out[b * NPTS + r0] = rnk[lab0];
    out[b * NPTS + r1] = rnk[lab1];
}

extern "C" void kernel_launch(void* const* d_in, const int* in_sizes, int n_in,
                              void* d_out, int out_size, void* d_ws, size_t ws_size,
                              hipStream_t stream) {
    const float* x  = (const float*)d_in[0];
    const float* W1 = (const float*)d_in[1];
    const float* b1 = (const float*)d_in[2];
    const float* W2 = (const float*)d_in[3];
    const float* b2 = (const float*)d_in[4];

    float* h = (float*)d_ws;
    float* feats = h + (size_t)MROWS * H1;
    int* out = (int*)d_out;

    mlp1_kernel<<<dim3(MROWS / 64, H1 / 128), 256, 0, stream>>>(x, W1, b1, h);
    mlp2_kernel<<<MROWS / 16, 256, 0, stream>>>(h, W2, b2, feats);
    ward_kernel<<<BB, 256, 0, stream>>>(feats, out);
}

// Round 10
// 431.028 us; speedup vs baseline: 1.2550x; 1.0479x over previous
//
#include <hip/hip_runtime.h>
#include <math.h>

#define BB 128
#define NN 128
#define DIN 1024
#define H1 256
#define DOUT 32
#define KCL 8
#define NPTS 128
#define MROWS (BB*NN)   // 16384
#define CSTR 130        // centsT row stride (words, init staging only)
#define RSTR 132        // cost/G row stride (words, 16B aligned)
#define DEADKEY 0xFFFFFFFF00000000ull

__device__ __forceinline__ float gelu_exact(float v) {
    return 0.5f * v * (1.0f + erff(v * 0.70710678118654752f));
}

__device__ __forceinline__ unsigned long long mkkey(float v, int r, int j) {
    return ((unsigned long long)__float_as_uint(v) << 32) | (unsigned)((r << 7) | j);
}

__device__ __forceinline__ float readlanef(float v, int lane) {
    return __int_as_float(__builtin_amdgcn_readlane(__float_as_int(v), lane));
}

// u32 min via DPP (costs are >=0 floats: IEEE order == unsigned bit order)
template<int CTRL, int RMASK>
__device__ __forceinline__ unsigned dpp_umin_step(unsigned v) {
    unsigned t = (unsigned)__builtin_amdgcn_update_dpp((int)v, (int)v, CTRL, RMASK, 0xf, false);
    return t < v ? t : v;
}
__device__ __forceinline__ unsigned wave_umin_bcast(unsigned v) {
    v = dpp_umin_step<0x111, 0xf>(v);
    v = dpp_umin_step<0x112, 0xf>(v);
    v = dpp_umin_step<0x114, 0xf>(v);
    v = dpp_umin_step<0x118, 0xf>(v);
    v = dpp_umin_step<0x142, 0xa>(v);
    v = dpp_umin_step<0x143, 0xc>(v);
    return (unsigned)__builtin_amdgcn_readlane((int)v, 63);
}
// lane31 = min(lanes0..31), lane63 = min(lanes32..63)
__device__ __forceinline__ unsigned half_umin(unsigned v) {
    v = dpp_umin_step<0x111, 0xf>(v);
    v = dpp_umin_step<0x112, 0xf>(v);
    v = dpp_umin_step<0x114, 0xf>(v);
    v = dpp_umin_step<0x118, 0xf>(v);
    v = dpp_umin_step<0x142, 0xa>(v);
    return v;
}

// ---------------- gelu precompute: gx = gelu(x), memory-bound ----------------
__global__ __launch_bounds__(256) void gelu_kernel(const float* __restrict__ x,
                                                   float* __restrict__ gx, int n4) {
    int i = blockIdx.x * 256 + threadIdx.x;
    const int stride = gridDim.x * 256;
    for (; i < n4; i += stride) {
        float4 v = ((const float4*)x)[i];
        v.x = gelu_exact(v.x);
        v.y = gelu_exact(v.y);
        v.z = gelu_exact(v.z);
        v.w = gelu_exact(v.w);
        ((float4*)gx)[i] = v;
    }
}

// ---------------- GEMM1: h = A @ W1 + b1 ; R4 structure (64x64, BK=32, grid 1024) ----------------
// FUSE=true: A = gelu(x) applied at staging (fallback). FUSE=false: A = gx (pre-gelu'd).
template<bool FUSE>
__global__ __launch_bounds__(256) void mlp1_kernel(const float* __restrict__ xin,
                                                   const float* __restrict__ W1,
                                                   const float* __restrict__ b1,
                                                   float* __restrict__ h) {
    __shared__ float As[32][68];  // [k][m]
    __shared__ float Bs[32][68];  // [k][n]
    const int bm = blockIdx.x;    // 256 row-tiles of 64
    const int bn = blockIdx.y;    // 4 col-tiles of 64
    const int tid = threadIdx.x;
    const int tx = tid & 15, ty = tid >> 4;

    float acc[4][4] = {{0.f}};

    const int arow = tid >> 2;         // 0..63
    const int acol4 = (tid & 3) * 4;   // k offset 0,4,8,12
    const int brow = tid >> 4;         // 0..15 (k)
    const int bcol4 = (tid & 15) * 4;  // 0..60

    const float* xrow = xin + (size_t)(bm * 64 + arow) * DIN;
    const float* wbase = W1 + bn * 64;

    for (int kt = 0; kt < DIN; kt += 32) {
        float4 a0 = *(const float4*)(xrow + kt + acol4);
        float4 a1 = *(const float4*)(xrow + kt + 16 + acol4);
        float4 w0 = *(const float4*)(wbase + (size_t)(kt + brow) * H1 + bcol4);
        float4 w1 = *(const float4*)(wbase + (size_t)(kt + 16 + brow) * H1 + bcol4);
        __syncthreads();
        if (FUSE) {
            As[acol4 + 0][arow] = gelu_exact(a0.x);
            As[acol4 + 1][arow] = gelu_exact(a0.y);
            As[acol4 + 2][arow] = gelu_exact(a0.z);
            As[acol4 + 3][arow] = gelu_exact(a0.w);
            As[16 + acol4 + 0][arow] = gelu_exact(a1.x);
            As[16 + acol4 + 1][arow] = gelu_exact(a1.y);
            As[16 + acol4 + 2][arow] = gelu_exact(a1.z);
            As[16 + acol4 + 3][arow] = gelu_exact(a1.w);
        } else {
            As[acol4 + 0][arow] = a0.x;
            As[acol4 + 1][arow] = a0.y;
            As[acol4 + 2][arow] = a0.z;
            As[acol4 + 3][arow] = a0.w;
            As[16 + acol4 + 0][arow] = a1.x;
            As[16 + acol4 + 1][arow] = a1.y;
            As[16 + acol4 + 2][arow] = a1.z;
            As[16 + acol4 + 3][arow] = a1.w;
        }
        *(float4*)&Bs[brow][bcol4] = w0;
        *(float4*)&Bs[16 + brow][bcol4] = w1;
        __syncthreads();
#pragma unroll
        for (int kk = 0; kk < 32; ++kk) {
            float4 a = *(const float4*)&As[kk][ty * 4];
            float4 b = *(const float4*)&Bs[kk][tx * 4];
            float ar[4] = {a.x, a.y, a.z, a.w};
            float br[4] = {b.x, b.y, b.z, b.w};
#pragma unroll
            for (int i = 0; i < 4; ++i)
#pragma unroll
                for (int j = 0; j < 4; ++j)
                    acc[i][j] = fmaf(ar[i], br[j], acc[i][j]);
        }
    }

    const int row = bm * 64 + ty * 4;
    const int col = bn * 64 + tx * 4;
    float4 bias = *(const float4*)(b1 + col);
#pragma unroll
    for (int i = 0; i < 4; ++i) {
        float4 o;
        o.x = acc[i][0] + bias.x;
        o.y = acc[i][1] + bias.y;
        o.z = acc[i][2] + bias.z;
        o.w = acc[i][3] + bias.w;
        *(float4*)(h + (size_t)(row + i) * H1 + col) = o;
    }
}

// ---------------- GEMM2: feats = gelu(h) @ W2 + b2 (best-measured R4 version) ----------------
__global__ __launch_bounds__(256) void mlp2_kernel(const float* __restrict__ h,
                                                   const float* __restrict__ W2,
                                                   const float* __restrict__ b2,
                                                   float* __restrict__ feats) {
    __shared__ float hs[16][257];
    __shared__ float w2s[H1 * DOUT];
    const int blk = blockIdx.x;
    const int tid = threadIdx.x;

    for (int i = tid; i < (H1 * DOUT) / 4; i += 256) {
        ((float4*)w2s)[i] = ((const float4*)W2)[i];
    }
    const float* hb = h + (size_t)blk * 16 * H1;
    for (int i = tid; i < (16 * H1) / 4; i += 256) {
        float4 v = ((const float4*)hb)[i];
        int r = i >> 6;
        int c = (i & 63) * 4;
        hs[r][c + 0] = gelu_exact(v.x);
        hs[r][c + 1] = gelu_exact(v.y);
        hs[r][c + 2] = gelu_exact(v.z);
        hs[r][c + 3] = gelu_exact(v.w);
    }
    __syncthreads();

    const int col = tid & 31;
    const int r0 = (tid >> 5) * 2;
    float acc0 = 0.f, acc1 = 0.f;
    for (int k = 0; k < H1; ++k) {
        float w = w2s[k * DOUT + col];
        acc0 = fmaf(hs[r0 + 0][k], w, acc0);
        acc1 = fmaf(hs[r0 + 1][k], w, acc1);
    }
    float bias = b2[col];
    const int rowg = blk * 16 + r0;
    feats[(size_t)(rowg + 0) * DOUT + col] = acc0 + bias;
    feats[(size_t)(rowg + 1) * DOUT + col] = acc1 + bias;
}

// ---------------- Ward clustering: incremental Gram, i2 folded into rescan loop ----------------
__global__ __launch_bounds__(256) void ward_kernel(const float* __restrict__ feats,
                                                   int* __restrict__ out) {
    __shared__ __align__(16) float cost[NPTS * RSTR];  // 67.6 KB
    __shared__ __align__(16) float G[NPTS * RSTR];     // 67.6 KB Gram matrix
    __shared__ float centsT[32 * CSTR];                // init staging only
    __shared__ unsigned long long rowkey[NPTS];
    __shared__ float sqArr[NPTS];
    __shared__ float szsE[NPTS];
    __shared__ int rnk[NPTS];

    const int b = blockIdx.x;
    const int tid = threadIdx.x;
    const float* f = feats + (size_t)b * NPTS * DOUT;
    const float INF = __builtin_inff();

    // ---- init (all 4 waves) ----
    for (int i = tid; i < NPTS * DOUT; i += 256) {
        int r = i >> 5, d = i & 31;
        centsT[d * CSTR + r] = f[i];
    }
    __syncthreads();
    if (tid < NPTS) {
        float s = 0.f;
#pragma unroll
        for (int d = 0; d < 32; ++d) {
            float v = centsT[d * CSTR + tid];
            s = fmaf(v, v, s);
        }
        sqArr[tid] = s;
    }
    __syncthreads();
    {
        int ti = tid >> 4, tj = tid & 15;
        int I0 = ti * 8, J0 = tj * 8;
        float acc[8][8];
#pragma unroll
        for (int u = 0; u < 8; ++u)
#pragma unroll
            for (int v = 0; v < 8; ++v) acc[u][v] = 0.f;
        for (int d = 0; d < 32; ++d) {
            float a[8], bb[8];
#pragma unroll
            for (int u = 0; u < 8; ++u) a[u] = centsT[d * CSTR + I0 + u];
#pragma unroll
            for (int v = 0; v < 8; ++v) bb[v] = centsT[d * CSTR + J0 + v];
#pragma unroll
            for (int u = 0; u < 8; ++u)
#pragma unroll
                for (int v = 0; v < 8; ++v)
                    acc[u][v] = fmaf(a[u], bb[v], acc[u][v]);
        }
#pragma unroll
        for (int u = 0; u < 8; ++u) {
#pragma unroll
            for (int v = 0; v < 8; ++v) {
                int i = I0 + u, j = J0 + v;
                G[i * RSTR + j] = acc[u][v];
                float d2 = sqArr[i] + sqArr[j] - 2.0f * acc[u][v];
                if (d2 < 0.f) d2 = 0.f;
                float w = (1.0f * 1.0f) / (1.0f + 1.0f + 1e-30f);
                cost[i * RSTR + j] = (i == j) ? INF : w * d2;
            }
        }
    }
    __syncthreads();
    if (tid < NPTS) {
        unsigned long long best = DEADKEY;
        for (int j = 0; j < NPTS; ++j) {
            float v = cost[tid * RSTR + j];
            unsigned long long k = mkkey(v, tid, j);
            if (k < best) best = k;
        }
        rowkey[tid] = best;
    }
    __syncthreads();

    if (tid >= 64) return;  // wave 0 only
    const int lane = tid;
    const int hh = lane & 31;
    const int r0 = lane * 2, r1 = lane * 2 + 1;

    unsigned long long k0 = rowkey[r0], k1 = rowkey[r1];
    float q0 = sqArr[r0], q1 = sqArr[r1];
    float s0 = 1.0f, s1 = 1.0f;
    int lab0 = r0, lab1 = r1;
    unsigned long long alive0 = ~0ull, alive1 = ~0ull;

    for (int it = 0; it < NPTS - KCL; ++it) {
        // P1: global argmin via u32-bits DPP min + ballot (exact flat-index tie-break)
        unsigned bv0 = (unsigned)(k0 >> 32), bv1 = (unsigned)(k1 >> 32);
        unsigned lmin = bv0 < bv1 ? bv0 : bv1;
        unsigned lflat = (bv0 <= bv1) ? (unsigned)(k0 & 0x3FFFu) : (unsigned)(k1 & 0x3FFFu);
        unsigned gmin = wave_umin_bcast(lmin);
        unsigned long long bmask = __ballot(lmin == gmin);
        int lsel = __ffsll(bmask) - 1;
        unsigned flat = (unsigned)__builtin_amdgcn_readlane((int)lflat, lsel);
        int ra = (int)(flat >> 7), ca = (int)(flat & 127u);
        const int i2 = ra < ca ? ra : ca;
        const int j2 = ra < ca ? ca : ra;

        // Gram rows i2, j2 (issued early; only depend on i2/j2)
        float2 gi = *(const float2*)&G[i2 * RSTR + r0];
        float2 gj = *(const float2*)&G[j2 * RSTR + r0];

        float si = readlanef((i2 & 1) ? s1 : s0, i2 >> 1);
        float sj = readlanef((j2 & 1) ? s1 : s0, j2 >> 1);
        const float snew = si + sj;
        const float invs = 1.0f / snew;
        const float wa = si * invs, wb = sj * invs;

        int arg0 = (int)(k0 & 127u), arg1 = (int)(k1 & 127u);
        bool d0 = (s0 > 0.f) && r0 != i2 && r0 != j2 && (arg0 == i2 || arg0 == j2);
        bool d1 = (s1 > 0.f) && r1 != i2 && r1 != j2 && (arg1 == i2 || arg1 == j2);
        unsigned long long m0 = __ballot(d0), m1 = __ballot(d1);

        // scalar Gram entries for qn
        float Gii = readlanef((i2 & 1) ? gi.y : gi.x, i2 >> 1);
        float Gij = readlanef((i2 & 1) ? gj.y : gj.x, i2 >> 1);
        float Gjj = readlanef((j2 & 1) ? gj.y : gj.x, j2 >> 1);
        float dotA = wa * Gii + wb * Gij;
        float dotB = wa * Gij + wb * Gjj;
        float qn = wa * dotA + wb * dotB;

        // per-lane dots with merged cluster (linear Gram update)
        float dot0 = wa * gi.x + wb * gj.x;
        float dot1 = wa * gi.y + wb * gj.y;

        // state updates
        if (lab0 == j2) lab0 = i2;
        if (lab1 == j2) lab1 = i2;
        if (r0 == i2) s0 = snew; else if (r0 == j2) { s0 = 0.f; k0 = DEADKEY; }
        if (r1 == i2) s1 = snew; else if (r1 == j2) { s1 = 0.f; k1 = DEADKEY; }
        if (j2 < 64) alive0 &= ~(1ull << j2); else alive1 &= ~(1ull << (j2 - 64));
        if (r0 == i2) { dot0 = qn; q0 = qn; }
        if (r1 == i2) { dot1 = qn; q1 = qn; }

        // G updates: row i2 (contiguous b64), column i2
        *(float2*)&G[i2 * RSTR + r0] = make_float2(dot0, dot1);
        G[r0 * RSTR + i2] = dot0;
        G[r1 * RSTR + i2] = dot1;

        // cost values for row/col i2
        bool w0 = (s0 > 0.f) && r0 != i2 && r0 != j2;
        bool w1 = (s1 > 0.f) && r1 != i2 && r1 != j2;
        if (w0) {
            float d2 = q0 + qn - 2.0f * dot0;
            if (d2 < 0.f) d2 = 0.f;
            float w = (s0 * snew) / (s0 + snew + 1e-30f);
            float v0 = w * d2;
            cost[r0 * RSTR + i2] = v0;
            cost[i2 * RSTR + r0] = v0;
            if (!d0) {
                unsigned long long nk = mkkey(v0, r0, i2);
                if (nk < k0) k0 = nk;
            }
        }
        if (w1) {
            float d2 = q1 + qn - 2.0f * dot1;
            if (d2 < 0.f) d2 = 0.f;
            float w = (s1 * snew) / (s1 + snew + 1e-30f);
            float v1 = w * d2;
            cost[r1 * RSTR + i2] = v1;
            cost[i2 * RSTR + r1] = v1;
            if (!d1) {
                unsigned long long nk = mkkey(v1, r1, i2);
                if (nk < k1) k1 = nk;
            }
        }

        // rescans: row i2 (always) + dirty rows; 2 rows/round, b128 + alive-mask + u32 half-min
        bool pi = true;
        unsigned long long mm0 = m0, mm1 = m1;
        while (pi | (mm0 != 0ull) | (mm1 != 0ull)) {
            int rA, rB;
            bool hasB = false;
            if (pi) { rA = i2; pi = false; }
            else if (mm0) { int t = __ffsll(mm0) - 1; rA = 2 * t; mm0 &= mm0 - 1; }
            else { int t = __ffsll(mm1) - 1; rA = 2 * t + 1; mm1 &= mm1 - 1; }
            if (mm0) { int t = __ffsll(mm0) - 1; rB = 2 * t; mm0 &= mm0 - 1; hasB = true; }
            else if (mm1) { int t = __ffsll(mm1) - 1; rB = 2 * t + 1; mm1 &= mm1 - 1; hasB = true; }
            else rB = rA;

            int r = (lane < 32) ? rA : rB;
            float4 cv = *(const float4*)&cost[r * RSTR + 4 * hh];
            unsigned long long word = (hh < 16) ? alive0 : alive1;
            unsigned nib = (unsigned)(word >> ((4 * hh) & 63)) & 0xFu;
            unsigned e0 = (nib & 1u) ? __float_as_uint(cv.x) : 0xFFFFFFFFu;
            unsigned e1 = (nib & 2u) ? __float_as_uint(cv.y) : 0xFFFFFFFFu;
            unsigned e2 = (nib & 4u) ? __float_as_uint(cv.z) : 0xFFFFFFFFu;
            unsigned e3 = (nib & 8u) ? __float_as_uint(cv.w) : 0xFFFFFFFFu;
            unsigned m = e0; int c = 0;
            if (e1 < m) { m = e1; c = 1; }
            if (e2 < m) { m = e2; c = 2; }
            if (e3 < m) { m = e3; c = 3; }
            int lcol = 4 * hh + c;
            unsigned hm = half_umin(m);
            unsigned vA = (unsigned)__builtin_amdgcn_readlane((int)hm, 31);
            unsigned vB = (unsigned)__builtin_amdgcn_readlane((int)hm, 63);
            unsigned vref = (lane < 32) ? vA : vB;
            unsigned long long msk = __ballot(m == vref);
            int laneA = __ffsll(msk & 0xFFFFFFFFull) - 1;
            int laneB = 32 + __ffsll(msk >> 32) - 1;
            int colA = __builtin_amdgcn_readlane(lcol, laneA);
            int colB = __builtin_amdgcn_readlane(lcol, laneB);
            unsigned long long keyA = ((unsigned long long)vA << 32) | (unsigned)((rA << 7) | colA);
            unsigned long long keyB = ((unsigned long long)vB << 32) | (unsigned)((rB << 7) | colB);
            if (lane == (rA >> 1)) { if (rA & 1) k1 = keyA; else k0 = keyA; }
            if (hasB && lane == (rB >> 1)) { if (rB & 1) k1 = keyB; else k0 = keyB; }
        }
    }

    // final relabel
    szsE[r0] = s0;
    szsE[r1] = s1;
    __asm__ volatile("s_waitcnt lgkmcnt(0)" ::: "memory");
    if (lane == 0) {
        int c = 0;
        for (int i = 0; i < NPTS; ++i) rnk[i] = (szsE[i] > 0.f) ? c++ : -1;
    }
    __asm__ volatile("s_waitcnt lgkmcnt(0)" ::: "memory");
    out[b * NPTS + r0] = rnk[lab0];
    out[b * NPTS + r1] = rnk[lab1];
}

extern "C" void kernel_launch(void* const* d_in, const int* in_sizes, int n_in,
                              void* d_out, int out_size, void* d_ws, size_t ws_size,
                              hipStream_t stream) {
    const float* x  = (const float*)d_in[0];
    const float* W1 = (const float*)d_in[1];
    const float* b1 = (const float*)d_in[2];
    const float* W2 = (const float*)d_in[3];
    const float* b2 = (const float*)d_in[4];

    float* h = (float*)d_ws;                          // 16 MB
    float* feats = h + (size_t)MROWS * H1;            // 2 MB
    float* gx = feats + (size_t)MROWS * DOUT;         // 64 MB (if it fits)
    int* out = (int*)d_out;

    const size_t need = ((size_t)MROWS * H1 + (size_t)MROWS * DOUT + (size_t)MROWS * DIN) * 4;
    const bool use_gx = ws_size >= need;

    if (use_gx) {
        gelu_kernel<<<2048, 256, 0, stream>>>(x, gx, MROWS * DIN / 4);
        mlp1_kernel<false><<<dim3(MROWS / 64, H1 / 64), 256, 0, stream>>>(gx, W1, b1, h);
    } else {
        mlp1_kernel<true><<<dim3(MROWS / 64, H1 / 64), 256, 0, stream>>>(x, W1, b1, h);
    }
    mlp2_kernel<<<MROWS / 16, 256, 0, stream>>>(h, W2, b2, feats);
    ward_kernel<<<BB, 256, 0, stream>>>(feats, out);
}